// Round 4
// baseline (289.098 us; speedup 1.0000x reference)
//
#include <hip/hip_runtime.h>

// Problem constants (B=8, T=2048, C=512, KEY=512)
#define BATCH 8
#define TSEQ  2048
#define CDIM  512
#define MTOK  (BATCH*TSEQ)   // 16384
#define NTRI  136            // 16*17/2 triangular 128x128 tiles per batch

typedef __attribute__((ext_vector_type(8))) short bf16x8;
typedef __attribute__((ext_vector_type(4))) float f32x4;

__device__ __forceinline__ unsigned short f2bf(float f) {
    union { float f; unsigned int u; } v; v.f = f;
    unsigned int r = v.u + 0x7FFF + ((v.u >> 16) & 1);
    return (unsigned short)(r >> 16);
}
__device__ __forceinline__ float bfl(unsigned short u) {
    union { unsigned int i; float f; } v; v.i = ((unsigned int)u) << 16; return v.f;
}

__device__ __forceinline__ f32x4 fzero() { f32x4 z = {0.f, 0.f, 0.f, 0.f}; return z; }

// async 16B global -> LDS (LDS side is wave-uniform base + lane*16)
__device__ __forceinline__ void gl2lds16(const void* g, void* l) {
    __builtin_amdgcn_global_load_lds(
        (const __attribute__((address_space(1))) unsigned int*)g,
        (__attribute__((address_space(3))) unsigned int*)l, 16, 0, 0);
}

// stage a 128x32 bf16 tile (src = &tile[0][0], row stride ld shorts) into buf[4096]
__device__ __forceinline__ void stage_tile(const unsigned short* src, size_t ld,
                                           unsigned short* buf, int t) {
    const unsigned short* s0 = src + (size_t)(t >> 2) * ld + (t & 3) * 8;
    gl2lds16(s0, &buf[t * 8]);
    gl2lds16(s0 + (size_t)64 * ld, &buf[2048 + t * 8]);
}

// ---------------- Stage 1: conversions ----------------
// Converts x->bf16, writes x into out[:,:,0:512], zeros out[:,:,512:1024]
// (attn half is accumulated with atomics by k_attn).
__global__ __launch_bounds__(256) void k_convert_x(const float* __restrict__ x,
                                                   unsigned short* __restrict__ xb,
                                                   float* __restrict__ out) {
    int i = blockIdx.x * blockDim.x + threadIdx.x;      // float4 index
    float4 v = ((const float4*)x)[i];
    ushort4 o;
    o.x = f2bf(v.x); o.y = f2bf(v.y); o.z = f2bf(v.z); o.w = f2bf(v.w);
    ((ushort4*)xb)[i] = o;
    int e = i * 4;
    int row = e >> 9;          // /512
    int c   = e & 511;
    *(float4*)(out + (size_t)row * 1024 + c) = v;
    float4 z = {0.f, 0.f, 0.f, 0.f};
    *(float4*)(out + (size_t)row * 1024 + 512 + c) = z;
}

__global__ __launch_bounds__(256) void k_convert_w(const float* __restrict__ w,
                                                   unsigned short* __restrict__ wb) {
    int i = blockIdx.x * blockDim.x + threadIdx.x;
    float4 v = ((const float4*)w)[i];
    ushort4 o;
    o.x = f2bf(v.x); o.y = f2bf(v.y); o.z = f2bf(v.z); o.w = f2bf(v.w);
    ((ushort4*)wb)[i] = o;
}

// ---------------- Stage 2: fused QKV projection (m97-style 128x128 GEMM) ----
__global__ __launch_bounds__(256) void k_qkv(const unsigned short* __restrict__ xb,
                                             const unsigned short* __restrict__ Wcat,
                                             const float* __restrict__ bq,
                                             const float* __restrict__ bk,
                                             const float* __restrict__ bv,
                                             unsigned short* __restrict__ QKb,
                                             unsigned short* __restrict__ Vt) {
    __shared__ __align__(16) unsigned short lds[8192];
    unsigned short* As = lds;
    unsigned short* Bs = lds + 4096;
    int m0 = blockIdx.x * 128, n0 = blockIdx.y * 128;
    int t = threadIdx.x, w = t >> 6, lane = t & 63, quad = lane >> 4, lane16 = lane & 15;
    int rowHalf = (w >> 1) * 64, colHalf = (w & 1) * 64;

    f32x4 acc[4][4];
#pragma unroll
    for (int i = 0; i < 4; i++)
#pragma unroll
        for (int j = 0; j < 4; j++) acc[i][j] = fzero();

    for (int k0 = 0; k0 < CDIM; k0 += 32) {
        stage_tile(xb + (size_t)m0 * 512 + k0, 512, As, t);
        stage_tile(Wcat + (size_t)n0 * 512 + k0, 512, Bs, t);
        __syncthreads();
        bf16x8 a[4], b[4];
#pragma unroll
        for (int mi = 0; mi < 4; mi++)
            a[mi] = *(const bf16x8*)&As[(rowHalf + mi * 16 + lane16) * 32 + quad * 8];
#pragma unroll
        for (int ni = 0; ni < 4; ni++)
            b[ni] = *(const bf16x8*)&Bs[(colHalf + ni * 16 + lane16) * 32 + quad * 8];
#pragma unroll
        for (int mi = 0; mi < 4; mi++)
#pragma unroll
            for (int ni = 0; ni < 4; ni++)
                acc[mi][ni] = __builtin_amdgcn_mfma_f32_16x16x32_bf16(a[mi], b[ni], acc[mi][ni], 0, 0, 0);
        __syncthreads();
    }

    int which = n0 >> 9;     // block-uniform: 0=Q, 1=K, 2=V
    if (which < 2) {
        const float* bias = which ? bk : bq;
#pragma unroll
        for (int ni = 0; ni < 4; ni++) {
            int n = (n0 & 511) + colHalf + ni * 16 + lane16;
            float bb = bias[n];
            int col = which * 512 + n;
#pragma unroll
            for (int mi = 0; mi < 4; mi++)
#pragma unroll
                for (int r = 0; r < 4; r++) {
                    int m = m0 + rowHalf + mi * 16 + quad * 4 + r;
                    QKb[(size_t)m * 1024 + col] = f2bf(acc[mi][ni][r] + bb);
                }
        }
    } else {
        // V: transpose 64x64 wave quadrant -> Vt[b][v][t] in two 32-col passes
        unsigned short* T = &lds[w * 2048];        // [32 v][64 t]
        int b = m0 >> 11, tbase = (m0 & 2047) + rowHalf;
#pragma unroll
        for (int p = 0; p < 2; p++) {
            __syncthreads();
#pragma unroll
            for (int j = 0; j < 2; j++) {
                int ni = p * 2 + j;
                int n = (n0 & 511) + colHalf + ni * 16 + lane16;
                float bb = bv[n];
                int vl = j * 16 + lane16;
#pragma unroll
                for (int mi = 0; mi < 4; mi++)
#pragma unroll
                    for (int r = 0; r < 4; r++)
                        T[vl * 64 + mi * 16 + quad * 4 + r] = f2bf(acc[mi][ni][r] + bb);
            }
            __syncthreads();
#pragma unroll
            for (int i = 0; i < 4; i++) {
                int vl = i * 8 + (lane >> 3);
                int tl = (lane & 7) * 8;
                int v = (n0 & 511) + colHalf + p * 32 + vl;
                *(uint4*)(Vt + ((size_t)(b * 512 + v)) * 2048 + tbase + tl) =
                    *(const uint4*)&T[vl * 64 + tl];
            }
        }
    }
}

// ---------------- Stage 3: S = QK^T over triangle; P tiles (128x128) + colsum
__global__ __launch_bounds__(256) void k_score(const unsigned short* __restrict__ QKb,
                                               unsigned short* __restrict__ Pbuf,
                                               float* __restrict__ colsum) {
    __shared__ __align__(16) unsigned short lds[16384];
    unsigned short* As = lds;
    unsigned short* Bs = lds + 4096;
    int idx = blockIdx.x, bb = blockIdx.y;
    int qt = (int)((sqrtf(8.0f * idx + 1.0f) - 1.0f) * 0.5f);
    while ((qt + 1) * (qt + 2) / 2 <= idx) qt++;
    while (qt * (qt + 1) / 2 > idx) qt--;
    int st = idx - qt * (qt + 1) / 2;
    int q0 = qt * 128, s0 = st * 128;

    int t = threadIdx.x, w = t >> 6, lane = t & 63, quad = lane >> 4, lane16 = lane & 15;
    int rowHalf = (w >> 1) * 64, colHalf = (w & 1) * 64;
    const unsigned short* Qrows = QKb + ((size_t)(bb * 2048 + q0)) * 1024;
    const unsigned short* Krows = QKb + ((size_t)(bb * 2048 + s0)) * 1024 + 512;

    f32x4 acc[4][4];
#pragma unroll
    for (int i = 0; i < 4; i++)
#pragma unroll
        for (int j = 0; j < 4; j++) acc[i][j] = fzero();

    for (int k0 = 0; k0 < CDIM; k0 += 32) {
        stage_tile(Qrows + k0, 1024, As, t);
        stage_tile(Krows + k0, 1024, Bs, t);
        __syncthreads();
        bf16x8 a[4], b[4];
#pragma unroll
        for (int mi = 0; mi < 4; mi++)
            a[mi] = *(const bf16x8*)&As[(rowHalf + mi * 16 + lane16) * 32 + quad * 8];
#pragma unroll
        for (int ni = 0; ni < 4; ni++)
            b[ni] = *(const bf16x8*)&Bs[(colHalf + ni * 16 + lane16) * 32 + quad * 8];
#pragma unroll
        for (int mi = 0; mi < 4; mi++)
#pragma unroll
            for (int ni = 0; ni < 4; ni++)
                acc[mi][ni] = __builtin_amdgcn_mfma_f32_16x16x32_bf16(a[mi], b[ni], acc[mi][ni], 0, 0, 0);
        __syncthreads();
    }

    const float scale = 0.044194173824159216f;  // 1/sqrt(512)
    unsigned short* T = &lds[w * 4096];         // [64 q][64 s] per wave
    float csum[4] = {0.f, 0.f, 0.f, 0.f};
#pragma unroll
    for (int ni = 0; ni < 4; ni++) {
        int s = s0 + colHalf + ni * 16 + lane16;
#pragma unroll
        for (int mi = 0; mi < 4; mi++)
#pragma unroll
            for (int r = 0; r < 4; r++) {
                int q = q0 + rowHalf + mi * 16 + quad * 4 + r;
                float p = 0.0f;
                if (s <= q) { p = __expf(acc[mi][ni][r] * scale); csum[ni] += p; }
                T[(mi * 16 + quad * 4 + r) * 64 + ni * 16 + lane16] = f2bf(p);
            }
    }
#pragma unroll
    for (int ni = 0; ni < 4; ni++) {
        float v = csum[ni];
        v += __shfl_xor(v, 16);
        v += __shfl_xor(v, 32);
        if (quad == 0)
            unsafeAtomicAdd(&colsum[bb * 2048 + s0 + colHalf + ni * 16 + lane16], v);
    }
    __syncthreads();
    unsigned short* tile = Pbuf + ((size_t)(bb * NTRI + idx)) * 16384;
#pragma unroll
    for (int i = 0; i < 8; i++) {
        int rl = i * 8 + (lane >> 3);
        int cl = (lane & 7) * 8;
        *(uint4*)(tile + (rowHalf + rl) * 128 + colHalf + cl) = *(const uint4*)&T[rl * 64 + cl];
    }
}

// ---------------- Stage 3b: invert colsum ----------------
__global__ __launch_bounds__(256) void k_invcs(float* __restrict__ cs) {
    int i = blockIdx.x * 256 + threadIdx.x;
    cs[i] = 1.0f / cs[i];
}

// ---------------- Stage 3c: Vn[v][s] = V[v][s] * inv_colsum[s] (in place) ---
__global__ __launch_bounds__(256) void k_vscale(unsigned short* __restrict__ Vt,
                                                const float* __restrict__ inv) {
    int idx = blockIdx.x * 256 + threadIdx.x;   // 16B unit (8 bf16)
    int s8  = idx & 255;
    int row = idx >> 8;                         // b*512 + v
    int b   = row >> 9;
    uint4 raw = ((const uint4*)Vt)[idx];
    const float* ip = inv + b * TSEQ + s8 * 8;
    unsigned int rr[4] = {raw.x, raw.y, raw.z, raw.w};
    unsigned int oo[4];
#pragma unroll
    for (int j = 0; j < 4; j++) {
        float f0 = bfl((unsigned short)(rr[j] & 0xffff)) * ip[j * 2];
        float f1 = bfl((unsigned short)(rr[j] >> 16))    * ip[j * 2 + 1];
        oo[j] = (unsigned int)f2bf(f0) | ((unsigned int)f2bf(f1) << 16);
    }
    uint4 o = {oo[0], oo[1], oo[2], oo[3]};
    ((uint4*)Vt)[idx] = o;
}

// ---------------- Stage 4: attn = P @ Vn^T, split-K + atomic accumulate -----
// Work table: 40 (qt, chunk) pieces per (b, v0), K-chunk = 512 (4 s-tiles),
// sorted longest-first. Work per block is 1..4 units (vs 1..16 before).
__device__ const unsigned char g_piece[40] = {
    // w=4 pieces (28): (qt<<2)|chunk
    (15<<2)|0,(15<<2)|1,(15<<2)|2,(15<<2)|3,
    (14<<2)|0,(14<<2)|1,(14<<2)|2,
    (13<<2)|0,(13<<2)|1,(13<<2)|2,
    (12<<2)|0,(12<<2)|1,(12<<2)|2,
    (11<<2)|0,(11<<2)|1,(11<<2)|2,
    (10<<2)|0,(10<<2)|1,
    ( 9<<2)|0,( 9<<2)|1,
    ( 8<<2)|0,( 8<<2)|1,
    ( 7<<2)|0,( 7<<2)|1,
    ( 6<<2)|0,( 5<<2)|0,( 4<<2)|0,( 3<<2)|0,
    // w=3 (4)
    (14<<2)|3,(10<<2)|2,( 6<<2)|1,( 2<<2)|0,
    // w=2 (4)
    (13<<2)|3,( 9<<2)|2,( 5<<2)|1,( 1<<2)|0,
    // w=1 (4)
    (12<<2)|3,( 8<<2)|2,( 4<<2)|1,( 0<<2)|0,
};

__global__ __launch_bounds__(256) void k_attn(const unsigned short* __restrict__ Pbuf,
                                              const unsigned short* __restrict__ Vt,
                                              float* __restrict__ out) {
    __shared__ __align__(16) unsigned short lds[8192];
    unsigned short* As = lds;
    unsigned short* Bs = lds + 4096;
    int piece = g_piece[blockIdx.x];
    int qt = piece >> 2, ck = piece & 3;
    int v0 = blockIdx.y * 128;
    int bb = blockIdx.z;
    int t = threadIdx.x, w = t >> 6, lane = t & 63, quad = lane >> 4, lane16 = lane & 15;
    int rowHalf = (w >> 1) * 64, colHalf = (w & 1) * 64;

    const unsigned short* Pb = Pbuf + ((size_t)(bb * NTRI + qt * (qt + 1) / 2)) * 16384;
    const unsigned short* Vb = Vt + ((size_t)(bb * 512 + v0)) * 2048;

    f32x4 acc[4][4];
#pragma unroll
    for (int i = 0; i < 4; i++)
#pragma unroll
        for (int j = 0; j < 4; j++) acc[i][j] = fzero();

    int Kstart = ck * 512;
    int Kend   = (qt + 1) * 128;
    if (Kend > Kstart + 512) Kend = Kstart + 512;

    for (int k0 = Kstart; k0 < Kend; k0 += 32) {
        int stt = k0 >> 7, kin = k0 & 127;
        stage_tile(Pb + (size_t)stt * 16384 + kin, 128, As, t);
        stage_tile(Vb + k0, 2048, Bs, t);
        __syncthreads();
        bf16x8 a[4], b[4];
#pragma unroll
        for (int mi = 0; mi < 4; mi++)
            a[mi] = *(const bf16x8*)&As[(rowHalf + mi * 16 + lane16) * 32 + quad * 8];
#pragma unroll
        for (int ni = 0; ni < 4; ni++)
            b[ni] = *(const bf16x8*)&Bs[(colHalf + ni * 16 + lane16) * 32 + quad * 8];
#pragma unroll
        for (int mi = 0; mi < 4; mi++)
#pragma unroll
            for (int ni = 0; ni < 4; ni++)
                acc[mi][ni] = __builtin_amdgcn_mfma_f32_16x16x32_bf16(a[mi], b[ni], acc[mi][ni], 0, 0, 0);
        __syncthreads();
    }

#pragma unroll
    for (int mi = 0; mi < 4; mi++)
#pragma unroll
        for (int ni = 0; ni < 4; ni++)
#pragma unroll
            for (int r = 0; r < 4; r++) {
                int q = qt * 128 + rowHalf + mi * 16 + quad * 4 + r;
                int v = v0 + colHalf + ni * 16 + lane16;
                unsafeAtomicAdd(&out[((size_t)(bb * 2048 + q)) * 1024 + 512 + v],
                                acc[mi][ni][r]);
            }
}

extern "C" void kernel_launch(void* const* d_in, const int* in_sizes, int n_in,
                              void* d_out, int out_size, void* d_ws, size_t ws_size,
                              hipStream_t stream) {
    const float* x  = (const float*)d_in[0];
    const float* Wq = (const float*)d_in[1];
    const float* bq = (const float*)d_in[2];
    const float* Wk = (const float*)d_in[3];
    const float* bk = (const float*)d_in[4];
    const float* Wv = (const float*)d_in[5];
    const float* bv = (const float*)d_in[6];
    float* out = (float*)d_out;

    char* ws = (char*)d_ws;
    size_t off = 0;
    auto alloc = [&](size_t bytes) -> void* {
        void* p = ws + off;
        off += (bytes + 255) & ~(size_t)255;
        return p;
    };
    unsigned short* QKb = (unsigned short*)alloc((size_t)MTOK * 1024 * 2);   // 33.5 MB
    unsigned short* Vt  = (unsigned short*)alloc((size_t)MTOK * CDIM * 2);   // 16.8 MB
    float* colsum = (float*)alloc((size_t)BATCH * TSEQ * 4);
    size_t mark = off;
    unsigned short* Wcat = (unsigned short*)alloc((size_t)3 * CDIM * CDIM * 2);
    unsigned short* xb   = (unsigned short*)alloc((size_t)MTOK * CDIM * 2);
    unsigned short* Pbuf = (unsigned short*)(ws + mark);   // aliases dead Wcat/xb
    (void)ws_size;

    // Stage 1: conversions (+ x into out[:,:,:512], zero out[:,:,512:])
    k_convert_x<<<(MTOK * CDIM / 4) / 256, 256, 0, stream>>>(x, xb, out);
    k_convert_w<<<(CDIM * CDIM / 4) / 256, 256, 0, stream>>>(Wq, Wcat);
    k_convert_w<<<(CDIM * CDIM / 4) / 256, 256, 0, stream>>>(Wk, Wcat + (size_t)CDIM * CDIM);
    k_convert_w<<<(CDIM * CDIM / 4) / 256, 256, 0, stream>>>(Wv, Wcat + (size_t)2 * CDIM * CDIM);

    // Stage 2: fused QKV projection
    k_qkv<<<dim3(MTOK / 128, 1536 / 128), 256, 0, stream>>>(xb, Wcat, bq, bk, bv, QKb, Vt);

    // Stage 3: S over triangle -> P tiles (bf16) + column sums of exp
    hipMemsetAsync(colsum, 0, (size_t)BATCH * TSEQ * 4, stream);
    k_score<<<dim3(NTRI, BATCH), 256, 0, stream>>>(QKb, Pbuf, colsum);

    // Stage 3b/3c: fold softmax denominator into V rows
    k_invcs<<<(BATCH * TSEQ) / 256, 256, 0, stream>>>(colsum);
    k_vscale<<<(MTOK * CDIM / 8) / 256, 256, 0, stream>>>(Vt, colsum);

    // Stage 4: attn = P @ Vn^T (split-K, balanced, atomic accumulate)
    k_attn<<<dim3(40, CDIM / 128, BATCH), 256, 0, stream>>>(Pbuf, Vt, out);
}

// Round 5
// 256.264 us; speedup vs baseline: 1.1281x; 1.1281x over previous
//
#include <hip/hip_runtime.h>

// Problem constants (B=8, T=2048, C=512, KEY=512)
#define BATCH 8
#define TSEQ  2048
#define CDIM  512
#define MTOK  (BATCH*TSEQ)   // 16384
#define NTRI  136            // 16*17/2 triangular 128x128 tiles per batch

typedef __attribute__((ext_vector_type(8))) short bf16x8;
typedef __attribute__((ext_vector_type(4))) float f32x4;

__device__ __forceinline__ unsigned short f2bf(float f) {
    union { float f; unsigned int u; } v; v.f = f;
    unsigned int r = v.u + 0x7FFF + ((v.u >> 16) & 1);
    return (unsigned short)(r >> 16);
}
__device__ __forceinline__ float bfl(unsigned short u) {
    union { unsigned int i; float f; } v; v.i = ((unsigned int)u) << 16; return v.f;
}

__device__ __forceinline__ f32x4 fzero() { f32x4 z = {0.f, 0.f, 0.f, 0.f}; return z; }

// async 16B global -> LDS (LDS side is wave-uniform base + lane*16)
__device__ __forceinline__ void gl2lds16(const void* g, void* l) {
    __builtin_amdgcn_global_load_lds(
        (const __attribute__((address_space(1))) unsigned int*)g,
        (__attribute__((address_space(3))) unsigned int*)l, 16, 0, 0);
}

// stage a 128x32 bf16 tile (src = &tile[0][0], row stride ld shorts) into buf[4096]
__device__ __forceinline__ void stage_tile(const unsigned short* src, size_t ld,
                                           unsigned short* buf, int t) {
    const unsigned short* s0 = src + (size_t)(t >> 2) * ld + (t & 3) * 8;
    gl2lds16(s0, &buf[t * 8]);
    gl2lds16(s0 + (size_t)64 * ld, &buf[2048 + t * 8]);
}

// ---------------- Stage 1: conversions ----------------
__global__ __launch_bounds__(256) void k_convert_x(const float* __restrict__ x,
                                                   unsigned short* __restrict__ xb,
                                                   float* __restrict__ out) {
    int i = blockIdx.x * blockDim.x + threadIdx.x;      // float4 index
    float4 v = ((const float4*)x)[i];
    ushort4 o;
    o.x = f2bf(v.x); o.y = f2bf(v.y); o.z = f2bf(v.z); o.w = f2bf(v.w);
    ((ushort4*)xb)[i] = o;
    int e = i * 4;
    int row = e >> 9;          // /512
    int c   = e & 511;
    *(float4*)(out + (size_t)row * 1024 + c) = v;
}

__global__ __launch_bounds__(256) void k_convert_w(const float* __restrict__ w,
                                                   unsigned short* __restrict__ wb) {
    int i = blockIdx.x * blockDim.x + threadIdx.x;
    float4 v = ((const float4*)w)[i];
    ushort4 o;
    o.x = f2bf(v.x); o.y = f2bf(v.y); o.z = f2bf(v.z); o.w = f2bf(v.w);
    ((ushort4*)wb)[i] = o;
}

// ---------------- Stage 2: fused QKV projection (m97-style 128x128 GEMM) ----
__global__ __launch_bounds__(256) void k_qkv(const unsigned short* __restrict__ xb,
                                             const unsigned short* __restrict__ Wcat,
                                             const float* __restrict__ bq,
                                             const float* __restrict__ bk,
                                             const float* __restrict__ bv,
                                             unsigned short* __restrict__ QKb,
                                             unsigned short* __restrict__ Vt) {
    __shared__ __align__(16) unsigned short lds[8192];
    unsigned short* As = lds;
    unsigned short* Bs = lds + 4096;
    int m0 = blockIdx.x * 128, n0 = blockIdx.y * 128;
    int t = threadIdx.x, w = t >> 6, lane = t & 63, quad = lane >> 4, lane16 = lane & 15;
    int rowHalf = (w >> 1) * 64, colHalf = (w & 1) * 64;

    f32x4 acc[4][4];
#pragma unroll
    for (int i = 0; i < 4; i++)
#pragma unroll
        for (int j = 0; j < 4; j++) acc[i][j] = fzero();

    for (int k0 = 0; k0 < CDIM; k0 += 32) {
        stage_tile(xb + (size_t)m0 * 512 + k0, 512, As, t);
        stage_tile(Wcat + (size_t)n0 * 512 + k0, 512, Bs, t);
        __syncthreads();
        bf16x8 a[4], b[4];
#pragma unroll
        for (int mi = 0; mi < 4; mi++)
            a[mi] = *(const bf16x8*)&As[(rowHalf + mi * 16 + lane16) * 32 + quad * 8];
#pragma unroll
        for (int ni = 0; ni < 4; ni++)
            b[ni] = *(const bf16x8*)&Bs[(colHalf + ni * 16 + lane16) * 32 + quad * 8];
#pragma unroll
        for (int mi = 0; mi < 4; mi++)
#pragma unroll
            for (int ni = 0; ni < 4; ni++)
                acc[mi][ni] = __builtin_amdgcn_mfma_f32_16x16x32_bf16(a[mi], b[ni], acc[mi][ni], 0, 0, 0);
        __syncthreads();
    }

    int which = n0 >> 9;     // block-uniform: 0=Q, 1=K, 2=V
    if (which < 2) {
        const float* bias = which ? bk : bq;
#pragma unroll
        for (int ni = 0; ni < 4; ni++) {
            int n = (n0 & 511) + colHalf + ni * 16 + lane16;
            float bb = bias[n];
            int col = which * 512 + n;
#pragma unroll
            for (int mi = 0; mi < 4; mi++)
#pragma unroll
                for (int r = 0; r < 4; r++) {
                    int m = m0 + rowHalf + mi * 16 + quad * 4 + r;
                    QKb[(size_t)m * 1024 + col] = f2bf(acc[mi][ni][r] + bb);
                }
        }
    } else {
        // V: transpose 64x64 wave quadrant -> Vt[b][v][t] in two 32-col passes
        unsigned short* T = &lds[w * 2048];        // [32 v][64 t]
        int b = m0 >> 11, tbase = (m0 & 2047) + rowHalf;
#pragma unroll
        for (int p = 0; p < 2; p++) {
            __syncthreads();
#pragma unroll
            for (int j = 0; j < 2; j++) {
                int ni = p * 2 + j;
                int n = (n0 & 511) + colHalf + ni * 16 + lane16;
                float bb = bv[n];
                int vl = j * 16 + lane16;
#pragma unroll
                for (int mi = 0; mi < 4; mi++)
#pragma unroll
                    for (int r = 0; r < 4; r++)
                        T[vl * 64 + mi * 16 + quad * 4 + r] = f2bf(acc[mi][ni][r] + bb);
            }
            __syncthreads();
#pragma unroll
            for (int i = 0; i < 4; i++) {
                int vl = i * 8 + (lane >> 3);
                int tl = (lane & 7) * 8;
                int v = (n0 & 511) + colHalf + p * 32 + vl;
                *(uint4*)(Vt + ((size_t)(b * 512 + v)) * 2048 + tbase + tl) =
                    *(const uint4*)&T[vl * 64 + tl];
            }
        }
    }
}

// ---------------- Stage 3: S = QK^T over triangle; P tiles (128x128) + colsum
__global__ __launch_bounds__(256) void k_score(const unsigned short* __restrict__ QKb,
                                               unsigned short* __restrict__ Pbuf,
                                               float* __restrict__ colsum) {
    __shared__ __align__(16) unsigned short lds[16384];
    unsigned short* As = lds;
    unsigned short* Bs = lds + 4096;
    int idx = blockIdx.x, bb = blockIdx.y;
    int qt = (int)((sqrtf(8.0f * idx + 1.0f) - 1.0f) * 0.5f);
    while ((qt + 1) * (qt + 2) / 2 <= idx) qt++;
    while (qt * (qt + 1) / 2 > idx) qt--;
    int st = idx - qt * (qt + 1) / 2;
    int q0 = qt * 128, s0 = st * 128;

    int t = threadIdx.x, w = t >> 6, lane = t & 63, quad = lane >> 4, lane16 = lane & 15;
    int rowHalf = (w >> 1) * 64, colHalf = (w & 1) * 64;
    const unsigned short* Qrows = QKb + ((size_t)(bb * 2048 + q0)) * 1024;
    const unsigned short* Krows = QKb + ((size_t)(bb * 2048 + s0)) * 1024 + 512;

    f32x4 acc[4][4];
#pragma unroll
    for (int i = 0; i < 4; i++)
#pragma unroll
        for (int j = 0; j < 4; j++) acc[i][j] = fzero();

    for (int k0 = 0; k0 < CDIM; k0 += 32) {
        stage_tile(Qrows + k0, 1024, As, t);
        stage_tile(Krows + k0, 1024, Bs, t);
        __syncthreads();
        bf16x8 a[4], b[4];
#pragma unroll
        for (int mi = 0; mi < 4; mi++)
            a[mi] = *(const bf16x8*)&As[(rowHalf + mi * 16 + lane16) * 32 + quad * 8];
#pragma unroll
        for (int ni = 0; ni < 4; ni++)
            b[ni] = *(const bf16x8*)&Bs[(colHalf + ni * 16 + lane16) * 32 + quad * 8];
#pragma unroll
        for (int mi = 0; mi < 4; mi++)
#pragma unroll
            for (int ni = 0; ni < 4; ni++)
                acc[mi][ni] = __builtin_amdgcn_mfma_f32_16x16x32_bf16(a[mi], b[ni], acc[mi][ni], 0, 0, 0);
        __syncthreads();
    }

    const float scale = 0.044194173824159216f;  // 1/sqrt(512)
    unsigned short* T = &lds[w * 4096];         // [64 q][64 s] per wave
    float csum[4] = {0.f, 0.f, 0.f, 0.f};
#pragma unroll
    for (int ni = 0; ni < 4; ni++) {
        int s = s0 + colHalf + ni * 16 + lane16;
#pragma unroll
        for (int mi = 0; mi < 4; mi++)
#pragma unroll
            for (int r = 0; r < 4; r++) {
                int q = q0 + rowHalf + mi * 16 + quad * 4 + r;
                float p = 0.0f;
                if (s <= q) { p = __expf(acc[mi][ni][r] * scale); csum[ni] += p; }
                T[(mi * 16 + quad * 4 + r) * 64 + ni * 16 + lane16] = f2bf(p);
            }
    }
#pragma unroll
    for (int ni = 0; ni < 4; ni++) {
        float v = csum[ni];
        v += __shfl_xor(v, 16);
        v += __shfl_xor(v, 32);
        if (quad == 0)
            unsafeAtomicAdd(&colsum[bb * 2048 + s0 + colHalf + ni * 16 + lane16], v);
    }
    __syncthreads();
    unsigned short* tile = Pbuf + ((size_t)(bb * NTRI + idx)) * 16384;
#pragma unroll
    for (int i = 0; i < 8; i++) {
        int rl = i * 8 + (lane >> 3);
        int cl = (lane & 7) * 8;
        *(uint4*)(tile + (rowHalf + rl) * 128 + colHalf + cl) = *(const uint4*)&T[rl * 64 + cl];
    }
}

// ---------------- Stage 3b: invert colsum ----------------
__global__ __launch_bounds__(256) void k_invcs(float* __restrict__ cs) {
    int i = blockIdx.x * 256 + threadIdx.x;
    cs[i] = 1.0f / cs[i];
}

// ---------------- Stage 3c: Vn[v][s] = V[v][s] * inv_colsum[s] (in place) ---
__global__ __launch_bounds__(256) void k_vscale(unsigned short* __restrict__ Vt,
                                                const float* __restrict__ inv) {
    int idx = blockIdx.x * 256 + threadIdx.x;   // 16B unit (8 bf16)
    int s8  = idx & 255;
    int row = idx >> 8;                         // b*512 + v
    int b   = row >> 9;
    uint4 raw = ((const uint4*)Vt)[idx];
    const float* ip = inv + b * TSEQ + s8 * 8;
    unsigned int rr[4] = {raw.x, raw.y, raw.z, raw.w};
    unsigned int oo[4];
#pragma unroll
    for (int j = 0; j < 4; j++) {
        float f0 = bfl((unsigned short)(rr[j] & 0xffff)) * ip[j * 2];
        float f1 = bfl((unsigned short)(rr[j] >> 16))    * ip[j * 2 + 1];
        oo[j] = (unsigned int)f2bf(f0) | ((unsigned int)f2bf(f1) << 16);
    }
    uint4 o = {oo[0], oo[1], oo[2], oo[3]};
    ((uint4*)Vt)[idx] = o;
}

// ---------------- Stage 4: attn = P @ Vn^T (128x128 GEMM, CU-pair balanced) -
// 1D grid of 512. Under round-robin dispatch, blocks i and i+256 share a CU.
// First 256 blocks carry qt=0..7 (work 1..8), second 256 carry qt=15..8
// (work 16..9): every CU pair sums to 17 K-units. Plain stores, no atomics.
__global__ __launch_bounds__(256) void k_attn(const unsigned short* __restrict__ Pbuf,
                                              const unsigned short* __restrict__ Vt,
                                              float* __restrict__ out) {
    __shared__ __align__(16) unsigned short lds[8192];
    unsigned short* As = lds;
    unsigned short* Bs = lds + 4096;
    int i = blockIdx.x;
    int slot = i & 255, half = i >> 8;
    int qt = half ? (15 - (slot >> 5)) : (slot >> 5);
    int bv = slot & 31;
    int bb = bv >> 2;
    int v0 = (bv & 3) * 128;
    int t = threadIdx.x, w = t >> 6, lane = t & 63, quad = lane >> 4, lane16 = lane & 15;
    int rowHalf = (w >> 1) * 64, colHalf = (w & 1) * 64;

    const unsigned short* Pb = Pbuf + ((size_t)(bb * NTRI + qt * (qt + 1) / 2)) * 16384;
    const unsigned short* Vb = Vt + ((size_t)(bb * 512 + v0)) * 2048;

    f32x4 acc[4][4];
#pragma unroll
    for (int ii = 0; ii < 4; ii++)
#pragma unroll
        for (int j = 0; j < 4; j++) acc[ii][j] = fzero();

    int Kend = (qt + 1) * 128;
    for (int k0 = 0; k0 < Kend; k0 += 32) {
        int stt = k0 >> 7, kin = k0 & 127;
        stage_tile(Pb + (size_t)stt * 16384 + kin, 128, As, t);
        stage_tile(Vb + k0, 2048, Bs, t);
        __syncthreads();
        bf16x8 a[4], b[4];
#pragma unroll
        for (int mi = 0; mi < 4; mi++)
            a[mi] = *(const bf16x8*)&As[(rowHalf + mi * 16 + lane16) * 32 + quad * 8];
#pragma unroll
        for (int ni = 0; ni < 4; ni++)
            b[ni] = *(const bf16x8*)&Bs[(colHalf + ni * 16 + lane16) * 32 + quad * 8];
#pragma unroll
        for (int mi = 0; mi < 4; mi++)
#pragma unroll
            for (int ni = 0; ni < 4; ni++)
                acc[mi][ni] = __builtin_amdgcn_mfma_f32_16x16x32_bf16(a[mi], b[ni], acc[mi][ni], 0, 0, 0);
        __syncthreads();
    }

#pragma unroll
    for (int mi = 0; mi < 4; mi++)
#pragma unroll
        for (int ni = 0; ni < 4; ni++)
#pragma unroll
            for (int r = 0; r < 4; r++) {
                int q = qt * 128 + rowHalf + mi * 16 + quad * 4 + r;
                int v = v0 + colHalf + ni * 16 + lane16;
                out[((size_t)(bb * 2048 + q)) * 1024 + 512 + v] = acc[mi][ni][r];
            }
}

extern "C" void kernel_launch(void* const* d_in, const int* in_sizes, int n_in,
                              void* d_out, int out_size, void* d_ws, size_t ws_size,
                              hipStream_t stream) {
    const float* x  = (const float*)d_in[0];
    const float* Wq = (const float*)d_in[1];
    const float* bq = (const float*)d_in[2];
    const float* Wk = (const float*)d_in[3];
    const float* bk = (const float*)d_in[4];
    const float* Wv = (const float*)d_in[5];
    const float* bv = (const float*)d_in[6];
    float* out = (float*)d_out;

    char* ws = (char*)d_ws;
    size_t off = 0;
    auto alloc = [&](size_t bytes) -> void* {
        void* p = ws + off;
        off += (bytes + 255) & ~(size_t)255;
        return p;
    };
    unsigned short* QKb = (unsigned short*)alloc((size_t)MTOK * 1024 * 2);   // 33.5 MB
    unsigned short* Vt  = (unsigned short*)alloc((size_t)MTOK * CDIM * 2);   // 16.8 MB
    float* colsum = (float*)alloc((size_t)BATCH * TSEQ * 4);
    size_t mark = off;
    unsigned short* Wcat = (unsigned short*)alloc((size_t)3 * CDIM * CDIM * 2);
    unsigned short* xb   = (unsigned short*)alloc((size_t)MTOK * CDIM * 2);
    unsigned short* Pbuf = (unsigned short*)(ws + mark);   // aliases dead Wcat/xb
    (void)ws_size;

    // Stage 1: conversions (+ copy x into out[:, :, 0:512])
    k_convert_x<<<(MTOK * CDIM / 4) / 256, 256, 0, stream>>>(x, xb, out);
    k_convert_w<<<(CDIM * CDIM / 4) / 256, 256, 0, stream>>>(Wq, Wcat);
    k_convert_w<<<(CDIM * CDIM / 4) / 256, 256, 0, stream>>>(Wk, Wcat + (size_t)CDIM * CDIM);
    k_convert_w<<<(CDIM * CDIM / 4) / 256, 256, 0, stream>>>(Wv, Wcat + (size_t)2 * CDIM * CDIM);

    // Stage 2: fused QKV projection
    k_qkv<<<dim3(MTOK / 128, 1536 / 128), 256, 0, stream>>>(xb, Wcat, bq, bk, bv, QKb, Vt);

    // Stage 3: S over triangle -> P tiles (bf16) + column sums of exp
    hipMemsetAsync(colsum, 0, (size_t)BATCH * TSEQ * 4, stream);
    k_score<<<dim3(NTRI, BATCH), 256, 0, stream>>>(QKb, Pbuf, colsum);

    // Stage 3b/3c: fold softmax denominator into V rows
    k_invcs<<<(BATCH * TSEQ) / 256, 256, 0, stream>>>(colsum);
    k_vscale<<<(MTOK * CDIM / 8) / 256, 256, 0, stream>>>(Vt, colsum);

    // Stage 4: attn = P @ Vn^T (balanced CU pairing, plain stores)
    k_attn<<<512, 256, 0, stream>>>(Pbuf, Vt, out);
}

// Round 6
// 253.651 us; speedup vs baseline: 1.1397x; 1.0103x over previous
//
#include <hip/hip_runtime.h>

// Problem constants (B=8, T=2048, C=512, KEY=512)
#define BATCH 8
#define TSEQ  2048
#define CDIM  512
#define MTOK  (BATCH*TSEQ)   // 16384
#define NTRI  136            // 16*17/2 triangular 128x128 tiles per batch

typedef __attribute__((ext_vector_type(8))) short bf16x8;
typedef __attribute__((ext_vector_type(4))) float f32x4;

__device__ __forceinline__ unsigned short f2bf(float f) {
    union { float f; unsigned int u; } v; v.f = f;
    unsigned int r = v.u + 0x7FFF + ((v.u >> 16) & 1);
    return (unsigned short)(r >> 16);
}
__device__ __forceinline__ float bfl(unsigned short u) {
    union { unsigned int i; float f; } v; v.i = ((unsigned int)u) << 16; return v.f;
}

__device__ __forceinline__ f32x4 fzero() { f32x4 z = {0.f, 0.f, 0.f, 0.f}; return z; }

// async 16B global -> LDS (LDS side is wave-uniform base + lane*16)
__device__ __forceinline__ void gl2lds16(const void* g, void* l) {
    __builtin_amdgcn_global_load_lds(
        (const __attribute__((address_space(1))) unsigned int*)g,
        (__attribute__((address_space(3))) unsigned int*)l, 16, 0, 0);
}

// stage a 128x32 bf16 tile (src = &tile[0][0], row stride ld shorts) into buf[4096]
__device__ __forceinline__ void stage_tile(const unsigned short* src, size_t ld,
                                           unsigned short* buf, int t) {
    const unsigned short* s0 = src + (size_t)(t >> 2) * ld + (t & 3) * 8;
    gl2lds16(s0, &buf[t * 8]);
    gl2lds16(s0 + (size_t)64 * ld, &buf[2048 + t * 8]);
}

// ---------------- Stage 1: conversions ----------------
__global__ __launch_bounds__(256) void k_convert_x(const float* __restrict__ x,
                                                   unsigned short* __restrict__ xb,
                                                   float* __restrict__ out) {
    int i = blockIdx.x * blockDim.x + threadIdx.x;      // float4 index
    float4 v = ((const float4*)x)[i];
    ushort4 o;
    o.x = f2bf(v.x); o.y = f2bf(v.y); o.z = f2bf(v.z); o.w = f2bf(v.w);
    ((ushort4*)xb)[i] = o;
    int e = i * 4;
    int row = e >> 9;          // /512
    int c   = e & 511;
    *(float4*)(out + (size_t)row * 1024 + c) = v;
}

__global__ __launch_bounds__(256) void k_convert_w(const float* __restrict__ w,
                                                   unsigned short* __restrict__ wb) {
    int i = blockIdx.x * blockDim.x + threadIdx.x;
    float4 v = ((const float4*)w)[i];
    ushort4 o;
    o.x = f2bf(v.x); o.y = f2bf(v.y); o.z = f2bf(v.z); o.w = f2bf(v.w);
    ((ushort4*)wb)[i] = o;
}

// ---------------- Stage 2: fused QKV projection (m97-style 128x128 GEMM) ----
// QK epilogue goes through per-wave LDS transpose (stride 72 shorts: banks
// spread for b16 scatter-writes, 144B rows keep uint4 16B alignment), then
// 8 coalesced 16B stores per thread (full 128B row segments, no partial
// HBM sectors). V epilogue transposes to Vt[b][v][t] as before.
__global__ __launch_bounds__(256) void k_qkv(const unsigned short* __restrict__ xb,
                                             const unsigned short* __restrict__ Wcat,
                                             const float* __restrict__ bq,
                                             const float* __restrict__ bk,
                                             const float* __restrict__ bv,
                                             unsigned short* __restrict__ QKb,
                                             unsigned short* __restrict__ Vt) {
    __shared__ __align__(16) unsigned short lds[18432];   // 36.9 KB
    unsigned short* As = lds;
    unsigned short* Bs = lds + 4096;
    int m0 = blockIdx.x * 128, n0 = blockIdx.y * 128;
    int t = threadIdx.x, w = t >> 6, lane = t & 63, quad = lane >> 4, lane16 = lane & 15;
    int rowHalf = (w >> 1) * 64, colHalf = (w & 1) * 64;

    f32x4 acc[4][4];
#pragma unroll
    for (int i = 0; i < 4; i++)
#pragma unroll
        for (int j = 0; j < 4; j++) acc[i][j] = fzero();

    for (int k0 = 0; k0 < CDIM; k0 += 32) {
        stage_tile(xb + (size_t)m0 * 512 + k0, 512, As, t);
        stage_tile(Wcat + (size_t)n0 * 512 + k0, 512, Bs, t);
        __syncthreads();
        bf16x8 a[4], b[4];
#pragma unroll
        for (int mi = 0; mi < 4; mi++)
            a[mi] = *(const bf16x8*)&As[(rowHalf + mi * 16 + lane16) * 32 + quad * 8];
#pragma unroll
        for (int ni = 0; ni < 4; ni++)
            b[ni] = *(const bf16x8*)&Bs[(colHalf + ni * 16 + lane16) * 32 + quad * 8];
#pragma unroll
        for (int mi = 0; mi < 4; mi++)
#pragma unroll
            for (int ni = 0; ni < 4; ni++)
                acc[mi][ni] = __builtin_amdgcn_mfma_f32_16x16x32_bf16(a[mi], b[ni], acc[mi][ni], 0, 0, 0);
        __syncthreads();
    }

    int which = n0 >> 9;     // block-uniform: 0=Q, 1=K, 2=V
    if (which < 2) {
        const float* bias = which ? bk : bq;
        unsigned short* T = &lds[w * 4608];   // per-wave [64][72]
#pragma unroll
        for (int ni = 0; ni < 4; ni++) {
            int n = (n0 & 511) + colHalf + ni * 16 + lane16;
            float bb = bias[n];
#pragma unroll
            for (int mi = 0; mi < 4; mi++)
#pragma unroll
                for (int r = 0; r < 4; r++)
                    T[(mi * 16 + quad * 4 + r) * 72 + ni * 16 + lane16] =
                        f2bf(acc[mi][ni][r] + bb);
        }
        // per-wave private buffer: no cross-wave sync needed
        int colBase = which * 512 + (n0 & 511) + colHalf;
#pragma unroll
        for (int i = 0; i < 8; i++) {
            int rl = i * 8 + (lane >> 3);
            int cl = (lane & 7) * 8;
            int m = m0 + rowHalf + rl;
            *(uint4*)(QKb + (size_t)m * 1024 + colBase + cl) = *(const uint4*)&T[rl * 72 + cl];
        }
    } else {
        // V: transpose 64x64 wave quadrant -> Vt[b][v][t] in two 32-col passes
        unsigned short* T = &lds[w * 2048];        // [32 v][64 t]
        int b = m0 >> 11, tbase = (m0 & 2047) + rowHalf;
#pragma unroll
        for (int p = 0; p < 2; p++) {
            __syncthreads();
#pragma unroll
            for (int j = 0; j < 2; j++) {
                int ni = p * 2 + j;
                int n = (n0 & 511) + colHalf + ni * 16 + lane16;
                float bb = bv[n];
                int vl = j * 16 + lane16;
#pragma unroll
                for (int mi = 0; mi < 4; mi++)
#pragma unroll
                    for (int r = 0; r < 4; r++)
                        T[vl * 64 + mi * 16 + quad * 4 + r] = f2bf(acc[mi][ni][r] + bb);
            }
            __syncthreads();
#pragma unroll
            for (int i = 0; i < 4; i++) {
                int vl = i * 8 + (lane >> 3);
                int tl = (lane & 7) * 8;
                int v = (n0 & 511) + colHalf + p * 32 + vl;
                *(uint4*)(Vt + ((size_t)(b * 512 + v)) * 2048 + tbase + tl) =
                    *(const uint4*)&T[vl * 64 + tl];
            }
        }
    }
}

// ---------------- Stage 3: S = QK^T over triangle; P tiles (128x128) + colsum
__global__ __launch_bounds__(256) void k_score(const unsigned short* __restrict__ QKb,
                                               unsigned short* __restrict__ Pbuf,
                                               float* __restrict__ colsum) {
    __shared__ __align__(16) unsigned short lds[16384];
    unsigned short* As = lds;
    unsigned short* Bs = lds + 4096;
    int idx = blockIdx.x, bb = blockIdx.y;
    int qt = (int)((sqrtf(8.0f * idx + 1.0f) - 1.0f) * 0.5f);
    while ((qt + 1) * (qt + 2) / 2 <= idx) qt++;
    while (qt * (qt + 1) / 2 > idx) qt--;
    int st = idx - qt * (qt + 1) / 2;
    int q0 = qt * 128, s0 = st * 128;

    int t = threadIdx.x, w = t >> 6, lane = t & 63, quad = lane >> 4, lane16 = lane & 15;
    int rowHalf = (w >> 1) * 64, colHalf = (w & 1) * 64;
    const unsigned short* Qrows = QKb + ((size_t)(bb * 2048 + q0)) * 1024;
    const unsigned short* Krows = QKb + ((size_t)(bb * 2048 + s0)) * 1024 + 512;

    f32x4 acc[4][4];
#pragma unroll
    for (int i = 0; i < 4; i++)
#pragma unroll
        for (int j = 0; j < 4; j++) acc[i][j] = fzero();

    for (int k0 = 0; k0 < CDIM; k0 += 32) {
        stage_tile(Qrows + k0, 1024, As, t);
        stage_tile(Krows + k0, 1024, Bs, t);
        __syncthreads();
        bf16x8 a[4], b[4];
#pragma unroll
        for (int mi = 0; mi < 4; mi++)
            a[mi] = *(const bf16x8*)&As[(rowHalf + mi * 16 + lane16) * 32 + quad * 8];
#pragma unroll
        for (int ni = 0; ni < 4; ni++)
            b[ni] = *(const bf16x8*)&Bs[(colHalf + ni * 16 + lane16) * 32 + quad * 8];
#pragma unroll
        for (int mi = 0; mi < 4; mi++)
#pragma unroll
            for (int ni = 0; ni < 4; ni++)
                acc[mi][ni] = __builtin_amdgcn_mfma_f32_16x16x32_bf16(a[mi], b[ni], acc[mi][ni], 0, 0, 0);
        __syncthreads();
    }

    const float scale = 0.044194173824159216f;  // 1/sqrt(512)
    unsigned short* T = &lds[w * 4096];         // [64 q][64 s] per wave
    float csum[4] = {0.f, 0.f, 0.f, 0.f};
#pragma unroll
    for (int ni = 0; ni < 4; ni++) {
        int s = s0 + colHalf + ni * 16 + lane16;
#pragma unroll
        for (int mi = 0; mi < 4; mi++)
#pragma unroll
            for (int r = 0; r < 4; r++) {
                int q = q0 + rowHalf + mi * 16 + quad * 4 + r;
                float p = 0.0f;
                if (s <= q) { p = __expf(acc[mi][ni][r] * scale); csum[ni] += p; }
                T[(mi * 16 + quad * 4 + r) * 64 + ni * 16 + lane16] = f2bf(p);
            }
    }
#pragma unroll
    for (int ni = 0; ni < 4; ni++) {
        float v = csum[ni];
        v += __shfl_xor(v, 16);
        v += __shfl_xor(v, 32);
        if (quad == 0)
            unsafeAtomicAdd(&colsum[bb * 2048 + s0 + colHalf + ni * 16 + lane16], v);
    }
    __syncthreads();
    unsigned short* tile = Pbuf + ((size_t)(bb * NTRI + idx)) * 16384;
#pragma unroll
    for (int i = 0; i < 8; i++) {
        int rl = i * 8 + (lane >> 3);
        int cl = (lane & 7) * 8;
        *(uint4*)(tile + (rowHalf + rl) * 128 + colHalf + cl) = *(const uint4*)&T[rl * 64 + cl];
    }
}

// ---------------- Stage 3b: invert colsum ----------------
__global__ __launch_bounds__(256) void k_invcs(float* __restrict__ cs) {
    int i = blockIdx.x * 256 + threadIdx.x;
    cs[i] = 1.0f / cs[i];
}

// ---------------- Stage 3c: Vn[v][s] = V[v][s] * inv_colsum[s] (in place) ---
__global__ __launch_bounds__(256) void k_vscale(unsigned short* __restrict__ Vt,
                                                const float* __restrict__ inv) {
    int idx = blockIdx.x * 256 + threadIdx.x;   // 16B unit (8 bf16)
    int s8  = idx & 255;
    int row = idx >> 8;                         // b*512 + v
    int b   = row >> 9;
    uint4 raw = ((const uint4*)Vt)[idx];
    const float* ip = inv + b * TSEQ + s8 * 8;
    unsigned int rr[4] = {raw.x, raw.y, raw.z, raw.w};
    unsigned int oo[4];
#pragma unroll
    for (int j = 0; j < 4; j++) {
        float f0 = bfl((unsigned short)(rr[j] & 0xffff)) * ip[j * 2];
        float f1 = bfl((unsigned short)(rr[j] >> 16))    * ip[j * 2 + 1];
        oo[j] = (unsigned int)f2bf(f0) | ((unsigned int)f2bf(f1) << 16);
    }
    uint4 o = {oo[0], oo[1], oo[2], oo[3]};
    ((uint4*)Vt)[idx] = o;
}

// ---------------- Stage 4: attn = P @ Vn^T (128x128 GEMM, CU-pair balanced) -
// 1D grid of 512. Under round-robin dispatch, blocks i and i+256 share a CU.
// First 256 blocks carry qt=0..7 (work 1..8), second 256 carry qt=15..8
// (work 16..9): every CU pair sums to 17 K-units. Plain stores, no atomics.
__global__ __launch_bounds__(256) void k_attn(const unsigned short* __restrict__ Pbuf,
                                              const unsigned short* __restrict__ Vt,
                                              float* __restrict__ out) {
    __shared__ __align__(16) unsigned short lds[8192];
    unsigned short* As = lds;
    unsigned short* Bs = lds + 4096;
    int i = blockIdx.x;
    int slot = i & 255, half = i >> 8;
    int qt = half ? (15 - (slot >> 5)) : (slot >> 5);
    int bv = slot & 31;
    int bb = bv >> 2;
    int v0 = (bv & 3) * 128;
    int t = threadIdx.x, w = t >> 6, lane = t & 63, quad = lane >> 4, lane16 = lane & 15;
    int rowHalf = (w >> 1) * 64, colHalf = (w & 1) * 64;

    const unsigned short* Pb = Pbuf + ((size_t)(bb * NTRI + qt * (qt + 1) / 2)) * 16384;
    const unsigned short* Vb = Vt + ((size_t)(bb * 512 + v0)) * 2048;

    f32x4 acc[4][4];
#pragma unroll
    for (int ii = 0; ii < 4; ii++)
#pragma unroll
        for (int j = 0; j < 4; j++) acc[ii][j] = fzero();

    int Kend = (qt + 1) * 128;
    for (int k0 = 0; k0 < Kend; k0 += 32) {
        int stt = k0 >> 7, kin = k0 & 127;
        stage_tile(Pb + (size_t)stt * 16384 + kin, 128, As, t);
        stage_tile(Vb + k0, 2048, Bs, t);
        __syncthreads();
        bf16x8 a[4], b[4];
#pragma unroll
        for (int mi = 0; mi < 4; mi++)
            a[mi] = *(const bf16x8*)&As[(rowHalf + mi * 16 + lane16) * 32 + quad * 8];
#pragma unroll
        for (int ni = 0; ni < 4; ni++)
            b[ni] = *(const bf16x8*)&Bs[(colHalf + ni * 16 + lane16) * 32 + quad * 8];
#pragma unroll
        for (int mi = 0; mi < 4; mi++)
#pragma unroll
            for (int ni = 0; ni < 4; ni++)
                acc[mi][ni] = __builtin_amdgcn_mfma_f32_16x16x32_bf16(a[mi], b[ni], acc[mi][ni], 0, 0, 0);
        __syncthreads();
    }

#pragma unroll
    for (int mi = 0; mi < 4; mi++)
#pragma unroll
        for (int ni = 0; ni < 4; ni++)
#pragma unroll
            for (int r = 0; r < 4; r++) {
                int q = qt * 128 + rowHalf + mi * 16 + quad * 4 + r;
                int v = v0 + colHalf + ni * 16 + lane16;
                out[((size_t)(bb * 2048 + q)) * 1024 + 512 + v] = acc[mi][ni][r];
            }
}

extern "C" void kernel_launch(void* const* d_in, const int* in_sizes, int n_in,
                              void* d_out, int out_size, void* d_ws, size_t ws_size,
                              hipStream_t stream) {
    const float* x  = (const float*)d_in[0];
    const float* Wq = (const float*)d_in[1];
    const float* bq = (const float*)d_in[2];
    const float* Wk = (const float*)d_in[3];
    const float* bk = (const float*)d_in[4];
    const float* Wv = (const float*)d_in[5];
    const float* bv = (const float*)d_in[6];
    float* out = (float*)d_out;

    char* ws = (char*)d_ws;
    size_t off = 0;
    auto alloc = [&](size_t bytes) -> void* {
        void* p = ws + off;
        off += (bytes + 255) & ~(size_t)255;
        return p;
    };
    unsigned short* QKb = (unsigned short*)alloc((size_t)MTOK * 1024 * 2);   // 33.5 MB
    unsigned short* Vt  = (unsigned short*)alloc((size_t)MTOK * CDIM * 2);   // 16.8 MB
    float* colsum = (float*)alloc((size_t)BATCH * TSEQ * 4);
    size_t mark = off;
    unsigned short* Wcat = (unsigned short*)alloc((size_t)3 * CDIM * CDIM * 2);
    unsigned short* xb   = (unsigned short*)alloc((size_t)MTOK * CDIM * 2);
    unsigned short* Pbuf = (unsigned short*)(ws + mark);   // aliases dead Wcat/xb
    (void)ws_size;

    // Stage 1: conversions (+ copy x into out[:, :, 0:512])
    k_convert_x<<<(MTOK * CDIM / 4) / 256, 256, 0, stream>>>(x, xb, out);
    k_convert_w<<<(CDIM * CDIM / 4) / 256, 256, 0, stream>>>(Wq, Wcat);
    k_convert_w<<<(CDIM * CDIM / 4) / 256, 256, 0, stream>>>(Wk, Wcat + (size_t)CDIM * CDIM);
    k_convert_w<<<(CDIM * CDIM / 4) / 256, 256, 0, stream>>>(Wv, Wcat + (size_t)2 * CDIM * CDIM);

    // Stage 2: fused QKV projection
    k_qkv<<<dim3(MTOK / 128, 1536 / 128), 256, 0, stream>>>(xb, Wcat, bq, bk, bv, QKb, Vt);

    // Stage 3: S over triangle -> P tiles (bf16) + column sums of exp
    hipMemsetAsync(colsum, 0, (size_t)BATCH * TSEQ * 4, stream);
    k_score<<<dim3(NTRI, BATCH), 256, 0, stream>>>(QKb, Pbuf, colsum);

    // Stage 3b/3c: fold softmax denominator into V rows
    k_invcs<<<(BATCH * TSEQ) / 256, 256, 0, stream>>>(colsum);
    k_vscale<<<(MTOK * CDIM / 8) / 256, 256, 0, stream>>>(Vt, colsum);

    // Stage 4: attn = P @ Vn^T (balanced CU pairing, plain stores)
    k_attn<<<512, 256, 0, stream>>>(Pbuf, Vt, out);
}